// Round 7
// baseline (287.002 us; speedup 1.0000x reference)
//
#include <hip/hip_runtime.h>
#include <math.h>

// LotkaVolterra neural-SDE rollout. P=4096, H=256, 100 sequential steps.
// R22 = R21 (proven ~222us steady: R16 main layers + swapped/__shfl tail)
// + PAIRED-COLUMN epilogue stores, zero register delta.
// The MFMA n-index -> output-column mapping is chosen by US (we load the
// B-fragment columns). Wave w now owns ADJACENT col pairs {w*32+2c, w*32+2c+1}
// instead of {w*32+c, w*32+16+c}: acc0[r]/acc1[r] become adjacent features of
// one path -> pack 2 bf16 into a u32 and store 4 ds_write_b32/lane instead of
// 8 scattered ds_write_b16. Bank map (16*(quad&1)+col+4r+16wv) mod 32 covers
// all 32 banks at 2 lanes each = conflict-free (2-way is free, m136); the old
// b16 pattern was 4-way (~1.58x). Downstream unchanged: feature c still lands
// at tile position c, so A-frag k-indices / W2,W3 k-maps / layer0 / tail are
// semantically identical. Only frag-col loader, bias indices, store loop move.
// Spill canary: FETCH ~16.6MB, WRITE ~38.4MB, VGPR 128 must hold.

#define PP 4096
#define HH 256
#define LT 100
#define PB 16
#define SH 264          // bf16 LDS row stride: 528 B = 33*16B (MUST stay 16B-multiple)
#define NT 512

typedef __attribute__((ext_vector_type(8))) short short8;
typedef __attribute__((ext_vector_type(4))) short short4v;
typedef __attribute__((ext_vector_type(4))) float float4v;

__device__ __forceinline__ float softplus_fast(float x) {
    const float e = __expf(-fabsf(x));
    return fmaxf(x, 0.0f) + __logf(1.0f + e);
}
__device__ __forceinline__ unsigned short f2bf(float f) {   // RNE fp32->bf16
    unsigned int u = __float_as_uint(f);
    u += 0x7fffu + ((u >> 16) & 1u);
    return (unsigned short)(u >> 16);
}
__device__ __forceinline__ float4 ldg4(const float* p) { return *(const float4*)p; }

// ---- parallel prologue: block b handles t = b+1 (R14-verified correct) ----
__global__ void prep_cfeat(const float* __restrict__ W0, const float* __restrict__ b0,
                           const float* __restrict__ feature_init,
                           const float* __restrict__ tn_store,
                           const float* __restrict__ x1_store,
                           const float* __restrict__ x2_store,
                           float* __restrict__ cfeat) {
    const int t = blockIdx.x + 1;             // 1..99
    const int col = threadIdx.x;
    // exact sequential fp32 tval chain (matches ref's scan accumulation)
    float tval = feature_init[0];
    for (int i = 0; i < t; ++i) tval += 0.1f;
    const float tn = tn_store[t - 1], x1 = x1_store[t - 1], x2 = x2_store[t - 1];
    const float w2c = W0[2 * 256 + col], w3c = W0[3 * 256 + col];
    const float w46 = W0[4 * 256 + col] + W0[6 * 256 + col];
    const float w57 = W0[5 * 256 + col] + W0[7 * 256 + col];
    cfeat[t * 256 + col] = b0[col] + tval * w2c + tn * w3c + x1 * w46 + x2 * w57;
}

// 256->256 bf16 MFMA layer, TWO ADJACENT col-groups/wave (paired-col mapping):
// acc0 = even cols wv*32+2c, acc1 = odd cols wv*32+2c+1 -> packed b32 stores.
__device__ __forceinline__ void mfma256_reg2(const short8 (&wf)[2][8], float bv0, float bv1,
                                             const unsigned short* __restrict__ hin,
                                             unsigned short* __restrict__ hout,
                                             int wv, int lane) {
    const int quad = lane >> 4, col = lane & 15;
    float4v acc0 = {bv0, bv0, bv0, bv0};
    float4v acc1 = {bv1, bv1, bv1, bv1};
    const unsigned short* arow = hin + col * SH + quad * 8;
#pragma unroll
    for (int ks = 0; ks < 8; ++ks) {
        short8 a = *(const short8*)(arow + ks * 32);
        acc0 = __builtin_amdgcn_mfma_f32_16x16x32_bf16(a, wf[0][ks], acc0, 0, 0, 0);
        acc1 = __builtin_amdgcn_mfma_f32_16x16x32_bf16(a, wf[1][ks], acc1, 0, 0, 0);
    }
    // C/D layout: col = lane&15, row p = quad*4 + reg (m89-verified).
    // acc0 holds feature wv*32+2col, acc1 holds wv*32+2col+1 -> one b32 store.
#pragma unroll
    for (int r = 0; r < 4; ++r) {
        const unsigned int lo = f2bf(fmaxf(acc0[r], 0.0f));
        const unsigned int hi = f2bf(fmaxf(acc1[r], 0.0f));
        *(unsigned int*)&hout[(quad * 4 + r) * SH + wv * 32 + 2 * col] = lo | (hi << 16);
    }
}

__global__ __launch_bounds__(NT, 2)
void lv_kernel(const float* __restrict__ W0, const float* __restrict__ b0,
               const float* __restrict__ W1, const float* __restrict__ b1,
               const float* __restrict__ W2, const float* __restrict__ b2,
               const float* __restrict__ W3, const float* __restrict__ b3,
               const float* __restrict__ obs_init, const float* __restrict__ feature_init,
               const float* __restrict__ path_seed,
               const float* __restrict__ cfeat,
               float* __restrict__ out) {
    __shared__ unsigned short hA[PB * SH];
    __shared__ unsigned short hB[PB * SH];
    __shared__ unsigned short hC[PB * SH];
    __shared__ __align__(16) unsigned short w3l[4096];   // W3 fragments (zero-padded)
    __shared__ __align__(16) float w0l[512];             // W0 rows 0,1
    __shared__ float st[PB][2];                          // path state
    __shared__ __align__(16) float pbuf[PB * 202];
    __shared__ __align__(16) float mbuf[PB * 200];
    __shared__ __align__(16) float sbuf[PB * 400];

    const int tid = threadIdx.x;
    const int lane = tid & 63;
    const int wv = tid >> 6;            // wave 0..7; owns col pairs wv*32+2c,+1
    const int quad = lane >> 4;
    const int col = lane & 15;
    const int hl = lane & 31;           // half-lane id (layer-0 col index base)
    const int lp = 2 * wv + (lane >> 5);// layer-0 path handled by this lane
    const int pbase = blockIdx.x * PB;

    const float DTf = 0.1f;
    const float SQ = 0.31622776601683794f;  // sqrt(0.1)

    // ---- per-wave W1/W2 B-fragments (2 ADJACENT col-groups) from global ----
    short8 wf1[2][8], wf2[2][8];
    {
#pragma unroll
        for (int g = 0; g < 2; ++g) {
            const int colc = wv * 32 + 2 * col + g;
#pragma unroll
            for (int ks = 0; ks < 8; ++ks) {
#pragma unroll
                for (int j = 0; j < 8; ++j) {
                    const int k = ks * 32 + quad * 8 + j;
                    wf1[g][ks][j] = (short)f2bf(W1[k * 256 + colc]);
                    wf2[g][ks][j] = (short)f2bf(W2[k * 256 + colc]);
                }
            }
        }
    }
    // ---- stage W3 fragments into LDS (zero-padded to 16 cols) ----
    for (int e = tid; e < 4096; e += NT) {
        const int j = e & 7, ln = (e >> 3) & 63, ks = e >> 9;
        const int k = ks * 32 + (ln >> 4) * 8 + j;
        const int n = ln & 15;
        w3l[e] = (n < 5) ? f2bf(W3[k * 5 + n]) : (unsigned short)0;
    }
    w0l[tid] = W0[tid];                      // rows 0,1 (NT == 512 exactly)

    // step-invariant hoists (paired-col bias indices)
    const float bv1a = b1[wv * 32 + 2 * col];
    const float bv1b = b1[wv * 32 + 2 * col + 1];
    const float bv2a = b2[wv * 32 + 2 * col];
    const float bv2b = b2[wv * 32 + 2 * col + 1];
    float4v b3v;                          // tail bias, D^T row n = quad*4+r
#pragma unroll
    for (int r = 0; r < 4; ++r) {
        const int n = quad * 4 + r;
        b3v[r] = (n < 5) ? b3[n] : 0.0f;
    }

    if (tid < PB) {
        const int p = tid, gp = pbase + p;
        pbuf[p * 202 + 0] = obs_init[gp * 2 + 0];
        pbuf[p * 202 + 101] = obs_init[gp * 2 + 1];
    }

    // ---- t=0 layer 0: lane handles path lp, 8 cols starting at hl*8 ----
    {
        const int gp = pbase + lp;
        float xk[8];
        xk[0] = obs_init[gp * 2 + 0];
        xk[1] = obs_init[gp * 2 + 1];
#pragma unroll
        for (int f = 0; f < 6; ++f) xk[2 + f] = feature_init[gp * 6 + f];
        const int c0 = hl * 8;
        float a[8];
        {
            const float4 ba = ldg4(b0 + c0);
            const float4 bb = ldg4(b0 + c0 + 4);
            a[0] = ba.x; a[1] = ba.y; a[2] = ba.z; a[3] = ba.w;
            a[4] = bb.x; a[5] = bb.y; a[6] = bb.z; a[7] = bb.w;
        }
#pragma unroll
        for (int k = 0; k < 8; ++k) {
            const float4 wa = ldg4(W0 + k * HH + c0);
            const float4 wb = ldg4(W0 + k * HH + c0 + 4);
            a[0] = fmaf(xk[k], wa.x, a[0]); a[1] = fmaf(xk[k], wa.y, a[1]);
            a[2] = fmaf(xk[k], wa.z, a[2]); a[3] = fmaf(xk[k], wa.w, a[3]);
            a[4] = fmaf(xk[k], wb.x, a[4]); a[5] = fmaf(xk[k], wb.y, a[5]);
            a[6] = fmaf(xk[k], wb.z, a[6]); a[7] = fmaf(xk[k], wb.w, a[7]);
        }
        short8 o;
#pragma unroll
        for (int j = 0; j < 8; ++j) o[j] = (short)f2bf(fmaxf(a[j], 0.0f));
        *(short8*)&hA[lp * SH + c0] = o;
    }
    // preload cfeat for t=1 (8 cols per lane)
    float4 cf0 = ldg4(cfeat + 256 + hl * 8);
    float4 cf1 = ldg4(cfeat + 256 + hl * 8 + 4);

    for (int t = 0; t < LT; ++t) {
        // seeds for this step: wave 0 lanes<16 only (it does the sampling)
        float e0 = 0.0f, e1 = 0.0f;
        if (tid < PB) {
            const int gp = pbase + tid;
            e0 = path_seed[(size_t)t * PP * 2 + gp * 2 + 0];
            e1 = path_seed[(size_t)t * PP * 2 + gp * 2 + 1];
        }

        // ---- layer 0 (t>=1): lane = path lp, 8 cols; st from LDS broadcast ----
        if (t > 0) {
            const float s0 = st[lp][0];
            const float s1 = st[lp][1];
            const int c0 = hl * 8;
            const float4 wa0 = *(const float4*)&w0l[c0];
            const float4 wa1 = *(const float4*)&w0l[c0 + 4];
            const float4 wb0 = *(const float4*)&w0l[256 + c0];
            const float4 wb1 = *(const float4*)&w0l[256 + c0 + 4];
            short8 o;
            o[0] = (short)f2bf(fmaxf(fmaf(s0, wa0.x, fmaf(s1, wb0.x, cf0.x)), 0.0f));
            o[1] = (short)f2bf(fmaxf(fmaf(s0, wa0.y, fmaf(s1, wb0.y, cf0.y)), 0.0f));
            o[2] = (short)f2bf(fmaxf(fmaf(s0, wa0.z, fmaf(s1, wb0.z, cf0.z)), 0.0f));
            o[3] = (short)f2bf(fmaxf(fmaf(s0, wa0.w, fmaf(s1, wb0.w, cf0.w)), 0.0f));
            o[4] = (short)f2bf(fmaxf(fmaf(s0, wa1.x, fmaf(s1, wb1.x, cf1.x)), 0.0f));
            o[5] = (short)f2bf(fmaxf(fmaf(s0, wa1.y, fmaf(s1, wb1.y, cf1.y)), 0.0f));
            o[6] = (short)f2bf(fmaxf(fmaf(s0, wa1.z, fmaf(s1, wb1.z, cf1.z)), 0.0f));
            o[7] = (short)f2bf(fmaxf(fmaf(s0, wa1.w, fmaf(s1, wb1.w, cf1.w)), 0.0f));
            *(short8*)&hA[lp * SH + c0] = o;
        }
        // prefetch next step's cfeat
        {
            const int ti = (t + 1 < LT) ? (t + 1) : (LT - 1);
            cf0 = ldg4(cfeat + ti * 256 + hl * 8);
            cf1 = ldg4(cfeat + ti * 256 + hl * 8 + 4);
        }
        __syncthreads();                       // B: h0 (hA) ready

        mfma256_reg2(wf1, bv1a, bv1b, hA, hB, wv, lane);   // h1 = relu(h0 @ W1 + b1)
        __syncthreads();                       // C: h1 (hB) ready
        mfma256_reg2(wf2, bv2a, bv2b, hB, hC, wv, lane);   // h2 = relu(h1 @ W2 + b2)
        __syncthreads();                       // D: h2 (hC) ready

        // ---- layer 3 + sampling: WAVE 0 ONLY. Operand-SWAPPED MFMA with W3
        //      frags from LDS (R18-verified); __shfl epilogue (R19-verified). ----
        if (wv == 0) {
            float4v accA = b3v;
            float4v accB = {0.0f, 0.0f, 0.0f, 0.0f};
            const unsigned short* arow = hC + col * SH + quad * 8;
#pragma unroll
            for (int ks = 0; ks < 4; ++ks) {    // two chains of 4 (halve dep latency)
                short8 a0 = *(const short8*)(arow + ks * 32);
                short8 a1 = *(const short8*)(arow + (ks + 4) * 32);
                short8 b0f = *(const short8*)(w3l + (ks * 64 + lane) * 8);
                short8 b1f = *(const short8*)(w3l + ((ks + 4) * 64 + lane) * 8);
                accA = __builtin_amdgcn_mfma_f32_16x16x32_bf16(b0f, a0, accA, 0, 0, 0);
                accB = __builtin_amdgcn_mfma_f32_16x16x32_bf16(b1f, a1, accB, 0, 0, 0);
            }
            // D^T: col = path p, row quad*4+r = output n. Lane(quad0,p): n=0..3;
            // lane(quad1,p): n=4 in reg 0. One shuffle brings s22 to quad0.
            const float4v s4 = accA + accB;
            const float s22r = __shfl(s4[0], (lane + 16) & 63);
            if (lane < 16) {
                const int p = lane;            // col == lane, quad == 0 here
                const float mu0 = s4[0];
                const float mu1 = s4[1];
                const float s11 = softplus_fast(s4[2]);
                const float s21 = s4[3];
                const float s22 = softplus_fast(s22r);
                const float ps0 = (t == 0) ? pbuf[p * 202 + 0] : st[p][0];
                const float ps1 = (t == 0) ? pbuf[p * 202 + 101] : st[p][1];
                const float n0 = softplus_fast(ps0 + DTf * mu0 + SQ * (s11 * e0));
                const float n1 = softplus_fast(ps1 + DTf * mu1 + SQ * (s21 * e0 + s22 * e1));
                st[p][0] = n0;
                st[p][1] = n1;
                pbuf[p * 202 + (t + 1)] = n0;
                pbuf[p * 202 + 101 + (t + 1)] = n1;
                mbuf[p * 200 + t * 2 + 0] = mu0;
                mbuf[p * 200 + t * 2 + 1] = mu1;
                sbuf[p * 400 + t * 4 + 0] = s11;
                sbuf[p * 400 + t * 4 + 1] = 0.0f;
                sbuf[p * 400 + t * 4 + 2] = s21;
                sbuf[p * 400 + t * 4 + 3] = s22;
            }
        }
        __syncthreads();                       // E: st ready for next layer0
    }

    // ---- coalesced output write phase ----
    float* __restrict__ pdst = out + (size_t)pbase * 202;
    float* __restrict__ mdst = out + (size_t)PP * 202 + (size_t)pbase * 200;
    float* __restrict__ sdst = out + (size_t)PP * 202 + (size_t)PP * 200 + (size_t)pbase * 400;
    for (int i = tid; i < PB * 202 / 4; i += NT) ((float4*)pdst)[i] = ((const float4*)pbuf)[i];
    for (int i = tid; i < PB * 200 / 4; i += NT) ((float4*)mdst)[i] = ((const float4*)mbuf)[i];
    for (int i = tid; i < PB * 400 / 4; i += NT) ((float4*)sdst)[i] = ((const float4*)sbuf)[i];
}

extern "C" void kernel_launch(void* const* d_in, const int* in_sizes, int n_in,
                              void* d_out, int out_size, void* d_ws, size_t ws_size,
                              hipStream_t stream) {
    (void)in_sizes; (void)n_in; (void)out_size; (void)ws_size;
    float* cfeat = (float*)d_ws;             // 100*256 fp32 = 100 KB
    prep_cfeat<<<LT - 1, 256, 0, stream>>>(
        (const float*)d_in[0],   // W0
        (const float*)d_in[1],   // b0
        (const float*)d_in[9],   // feature_init (t0)
        (const float*)d_in[10],  // tn_store
        (const float*)d_in[11],  // x1_store
        (const float*)d_in[12],  // x2_store
        cfeat);
    lv_kernel<<<PP / PB, NT, 0, stream>>>(
        (const float*)d_in[0],   // W0
        (const float*)d_in[1],   // b0
        (const float*)d_in[2],   // W1
        (const float*)d_in[3],   // b1
        (const float*)d_in[4],   // W2
        (const float*)d_in[5],   // b2
        (const float*)d_in[6],   // W3
        (const float*)d_in[7],   // b3
        (const float*)d_in[8],   // obs_init
        (const float*)d_in[9],   // feature_init
        (const float*)d_in[13],  // path_seed
        cfeat,
        (float*)d_out);
}

// Round 8
// 277.048 us; speedup vs baseline: 1.0359x; 1.0359x over previous
//
#include <hip/hip_runtime.h>
#include <math.h>

// LotkaVolterra neural-SDE rollout. P=4096, H=256, 100 sequential steps.
// R23 = R22 (222us steady: R16 main layers + paired-col b32 epilogue stores +
// swapped/__shfl wave-0 tail) + v_cvt_pk_bf16_f32 packing.
// Evidence: SQ_LDS_BANK_CONFLICT is bit-identical (1.740e7) across 4 variants
// with different LDS write patterns -> the counter tracks intrinsic wave64
// 2-lane/bank aliasing (free, m136), not a fixable cost. A-read bank map is
// provably balanced (8 dwords/bank). Remaining measured slack: VALUBusy 28.7%
// ~= 1500 cyc/step, of which ~80 VALU/lane/step is the MANUAL 4-instr RNE
// f2bf. gfx950's v_cvt_pk_bf16_f32 does 2 f32 -> packed 2xbf16 in ONE VALU op
// (RNE, matches f2bf bit-exactly), and its u32 result IS R22's paired-col b32
// store operand. Register-neutral; epilogue VALU sits on the MFMA->barrier
// critical path. Canary: VGPR 128, FETCH ~18.4MB, WRITE ~42MB must hold.

#define PP 4096
#define HH 256
#define LT 100
#define PB 16
#define SH 264          // bf16 LDS row stride: 528 B = 33*16B (MUST stay 16B-multiple)
#define NT 512

typedef __attribute__((ext_vector_type(8))) short short8;
typedef __attribute__((ext_vector_type(4))) short short4v;
typedef __attribute__((ext_vector_type(4))) float float4v;

__device__ __forceinline__ float softplus_fast(float x) {
    const float e = __expf(-fabsf(x));
    return fmaxf(x, 0.0f) + __logf(1.0f + e);
}
__device__ __forceinline__ unsigned short f2bf(float f) {   // RNE fp32->bf16 (host-side-ish uses)
    unsigned int u = __float_as_uint(f);
    u += 0x7fffu + ((u >> 16) & 1u);
    return (unsigned short)(u >> 16);
}
// one-instruction packed RNE conversion: D = {lo16: bf16(a), hi16: bf16(b)}
__device__ __forceinline__ unsigned int cvtpk(float a, float b) {
    unsigned int r;
    asm("v_cvt_pk_bf16_f32 %0, %1, %2" : "=v"(r) : "v"(a), "v"(b));
    return r;
}
__device__ __forceinline__ float4 ldg4(const float* p) { return *(const float4*)p; }

// ---- parallel prologue: block b handles t = b+1 (R14-verified correct) ----
__global__ void prep_cfeat(const float* __restrict__ W0, const float* __restrict__ b0,
                           const float* __restrict__ feature_init,
                           const float* __restrict__ tn_store,
                           const float* __restrict__ x1_store,
                           const float* __restrict__ x2_store,
                           float* __restrict__ cfeat) {
    const int t = blockIdx.x + 1;             // 1..99
    const int col = threadIdx.x;
    // exact sequential fp32 tval chain (matches ref's scan accumulation)
    float tval = feature_init[0];
    for (int i = 0; i < t; ++i) tval += 0.1f;
    const float tn = tn_store[t - 1], x1 = x1_store[t - 1], x2 = x2_store[t - 1];
    const float w2c = W0[2 * 256 + col], w3c = W0[3 * 256 + col];
    const float w46 = W0[4 * 256 + col] + W0[6 * 256 + col];
    const float w57 = W0[5 * 256 + col] + W0[7 * 256 + col];
    cfeat[t * 256 + col] = b0[col] + tval * w2c + tn * w3c + x1 * w46 + x2 * w57;
}

// 256->256 bf16 MFMA layer, TWO ADJACENT col-groups/wave (paired-col mapping):
// acc0 = even cols wv*32+2c, acc1 = odd cols wv*32+2c+1 -> one cvt_pk + one
// b32 store per r (epilogue = 4 fmax-pairs + 4 cvt_pk + 4 ds_write_b32).
__device__ __forceinline__ void mfma256_reg2(const short8 (&wf)[2][8], float bv0, float bv1,
                                             const unsigned short* __restrict__ hin,
                                             unsigned short* __restrict__ hout,
                                             int wv, int lane) {
    const int quad = lane >> 4, col = lane & 15;
    float4v acc0 = {bv0, bv0, bv0, bv0};
    float4v acc1 = {bv1, bv1, bv1, bv1};
    const unsigned short* arow = hin + col * SH + quad * 8;
#pragma unroll
    for (int ks = 0; ks < 8; ++ks) {
        short8 a = *(const short8*)(arow + ks * 32);
        acc0 = __builtin_amdgcn_mfma_f32_16x16x32_bf16(a, wf[0][ks], acc0, 0, 0, 0);
        acc1 = __builtin_amdgcn_mfma_f32_16x16x32_bf16(a, wf[1][ks], acc1, 0, 0, 0);
    }
    // C/D layout: col = lane&15, row p = quad*4 + reg (m89-verified).
#pragma unroll
    for (int r = 0; r < 4; ++r) {
        const unsigned int pk = cvtpk(fmaxf(acc0[r], 0.0f), fmaxf(acc1[r], 0.0f));
        *(unsigned int*)&hout[(quad * 4 + r) * SH + wv * 32 + 2 * col] = pk;
    }
}

__global__ __launch_bounds__(NT, 2)
void lv_kernel(const float* __restrict__ W0, const float* __restrict__ b0,
               const float* __restrict__ W1, const float* __restrict__ b1,
               const float* __restrict__ W2, const float* __restrict__ b2,
               const float* __restrict__ W3, const float* __restrict__ b3,
               const float* __restrict__ obs_init, const float* __restrict__ feature_init,
               const float* __restrict__ path_seed,
               const float* __restrict__ cfeat,
               float* __restrict__ out) {
    __shared__ unsigned short hA[PB * SH];
    __shared__ unsigned short hB[PB * SH];
    __shared__ unsigned short hC[PB * SH];
    __shared__ __align__(16) unsigned short w3l[4096];   // W3 fragments (zero-padded)
    __shared__ __align__(16) float w0l[512];             // W0 rows 0,1
    __shared__ float st[PB][2];                          // path state
    __shared__ __align__(16) float pbuf[PB * 202];
    __shared__ __align__(16) float mbuf[PB * 200];
    __shared__ __align__(16) float sbuf[PB * 400];

    const int tid = threadIdx.x;
    const int lane = tid & 63;
    const int wv = tid >> 6;            // wave 0..7; owns col pairs wv*32+2c,+1
    const int quad = lane >> 4;
    const int col = lane & 15;
    const int hl = lane & 31;           // half-lane id (layer-0 col index base)
    const int lp = 2 * wv + (lane >> 5);// layer-0 path handled by this lane
    const int pbase = blockIdx.x * PB;

    const float DTf = 0.1f;
    const float SQ = 0.31622776601683794f;  // sqrt(0.1)

    // ---- per-wave W1/W2 B-fragments (2 ADJACENT col-groups) from global ----
    short8 wf1[2][8], wf2[2][8];
    {
#pragma unroll
        for (int g = 0; g < 2; ++g) {
            const int colc = wv * 32 + 2 * col + g;
#pragma unroll
            for (int ks = 0; ks < 8; ++ks) {
#pragma unroll
                for (int j = 0; j < 8; ++j) {
                    const int k = ks * 32 + quad * 8 + j;
                    wf1[g][ks][j] = (short)f2bf(W1[k * 256 + colc]);
                    wf2[g][ks][j] = (short)f2bf(W2[k * 256 + colc]);
                }
            }
        }
    }
    // ---- stage W3 fragments into LDS (zero-padded to 16 cols) ----
    for (int e = tid; e < 4096; e += NT) {
        const int j = e & 7, ln = (e >> 3) & 63, ks = e >> 9;
        const int k = ks * 32 + (ln >> 4) * 8 + j;
        const int n = ln & 15;
        w3l[e] = (n < 5) ? f2bf(W3[k * 5 + n]) : (unsigned short)0;
    }
    w0l[tid] = W0[tid];                      // rows 0,1 (NT == 512 exactly)

    // step-invariant hoists (paired-col bias indices)
    const float bv1a = b1[wv * 32 + 2 * col];
    const float bv1b = b1[wv * 32 + 2 * col + 1];
    const float bv2a = b2[wv * 32 + 2 * col];
    const float bv2b = b2[wv * 32 + 2 * col + 1];
    float4v b3v;                          // tail bias, D^T row n = quad*4+r
#pragma unroll
    for (int r = 0; r < 4; ++r) {
        const int n = quad * 4 + r;
        b3v[r] = (n < 5) ? b3[n] : 0.0f;
    }

    if (tid < PB) {
        const int p = tid, gp = pbase + p;
        pbuf[p * 202 + 0] = obs_init[gp * 2 + 0];
        pbuf[p * 202 + 101] = obs_init[gp * 2 + 1];
    }

    // ---- t=0 layer 0: lane handles path lp, 8 cols starting at hl*8 ----
    {
        const int gp = pbase + lp;
        float xk[8];
        xk[0] = obs_init[gp * 2 + 0];
        xk[1] = obs_init[gp * 2 + 1];
#pragma unroll
        for (int f = 0; f < 6; ++f) xk[2 + f] = feature_init[gp * 6 + f];
        const int c0 = hl * 8;
        float a[8];
        {
            const float4 ba = ldg4(b0 + c0);
            const float4 bb = ldg4(b0 + c0 + 4);
            a[0] = ba.x; a[1] = ba.y; a[2] = ba.z; a[3] = ba.w;
            a[4] = bb.x; a[5] = bb.y; a[6] = bb.z; a[7] = bb.w;
        }
#pragma unroll
        for (int k = 0; k < 8; ++k) {
            const float4 wa = ldg4(W0 + k * HH + c0);
            const float4 wb = ldg4(W0 + k * HH + c0 + 4);
            a[0] = fmaf(xk[k], wa.x, a[0]); a[1] = fmaf(xk[k], wa.y, a[1]);
            a[2] = fmaf(xk[k], wa.z, a[2]); a[3] = fmaf(xk[k], wa.w, a[3]);
            a[4] = fmaf(xk[k], wb.x, a[4]); a[5] = fmaf(xk[k], wb.y, a[5]);
            a[6] = fmaf(xk[k], wb.z, a[6]); a[7] = fmaf(xk[k], wb.w, a[7]);
        }
        uint4 ov;
        ov.x = cvtpk(fmaxf(a[0], 0.0f), fmaxf(a[1], 0.0f));
        ov.y = cvtpk(fmaxf(a[2], 0.0f), fmaxf(a[3], 0.0f));
        ov.z = cvtpk(fmaxf(a[4], 0.0f), fmaxf(a[5], 0.0f));
        ov.w = cvtpk(fmaxf(a[6], 0.0f), fmaxf(a[7], 0.0f));
        *(uint4*)&hA[lp * SH + c0] = ov;
    }
    // preload cfeat for t=1 (8 cols per lane)
    float4 cf0 = ldg4(cfeat + 256 + hl * 8);
    float4 cf1 = ldg4(cfeat + 256 + hl * 8 + 4);

    for (int t = 0; t < LT; ++t) {
        // seeds for this step: wave 0 lanes<16 only (it does the sampling)
        float e0 = 0.0f, e1 = 0.0f;
        if (tid < PB) {
            const int gp = pbase + tid;
            e0 = path_seed[(size_t)t * PP * 2 + gp * 2 + 0];
            e1 = path_seed[(size_t)t * PP * 2 + gp * 2 + 1];
        }

        // ---- layer 0 (t>=1): lane = path lp, 8 cols; st from LDS broadcast ----
        if (t > 0) {
            const float s0 = st[lp][0];
            const float s1 = st[lp][1];
            const int c0 = hl * 8;
            const float4 wa0 = *(const float4*)&w0l[c0];
            const float4 wa1 = *(const float4*)&w0l[c0 + 4];
            const float4 wb0 = *(const float4*)&w0l[256 + c0];
            const float4 wb1 = *(const float4*)&w0l[256 + c0 + 4];
            uint4 ov;
            ov.x = cvtpk(fmaxf(fmaf(s0, wa0.x, fmaf(s1, wb0.x, cf0.x)), 0.0f),
                         fmaxf(fmaf(s0, wa0.y, fmaf(s1, wb0.y, cf0.y)), 0.0f));
            ov.y = cvtpk(fmaxf(fmaf(s0, wa0.z, fmaf(s1, wb0.z, cf0.z)), 0.0f),
                         fmaxf(fmaf(s0, wa0.w, fmaf(s1, wb0.w, cf0.w)), 0.0f));
            ov.z = cvtpk(fmaxf(fmaf(s0, wa1.x, fmaf(s1, wb1.x, cf1.x)), 0.0f),
                         fmaxf(fmaf(s0, wa1.y, fmaf(s1, wb1.y, cf1.y)), 0.0f));
            ov.w = cvtpk(fmaxf(fmaf(s0, wa1.z, fmaf(s1, wb1.z, cf1.z)), 0.0f),
                         fmaxf(fmaf(s0, wa1.w, fmaf(s1, wb1.w, cf1.w)), 0.0f));
            *(uint4*)&hA[lp * SH + c0] = ov;
        }
        // prefetch next step's cfeat
        {
            const int ti = (t + 1 < LT) ? (t + 1) : (LT - 1);
            cf0 = ldg4(cfeat + ti * 256 + hl * 8);
            cf1 = ldg4(cfeat + ti * 256 + hl * 8 + 4);
        }
        __syncthreads();                       // B: h0 (hA) ready

        mfma256_reg2(wf1, bv1a, bv1b, hA, hB, wv, lane);   // h1 = relu(h0 @ W1 + b1)
        __syncthreads();                       // C: h1 (hB) ready
        mfma256_reg2(wf2, bv2a, bv2b, hB, hC, wv, lane);   // h2 = relu(h1 @ W2 + b2)
        __syncthreads();                       // D: h2 (hC) ready

        // ---- layer 3 + sampling: WAVE 0 ONLY. Operand-SWAPPED MFMA with W3
        //      frags from LDS (R18-verified); __shfl epilogue (R19-verified). ----
        if (wv == 0) {
            float4v accA = b3v;
            float4v accB = {0.0f, 0.0f, 0.0f, 0.0f};
            const unsigned short* arow = hC + col * SH + quad * 8;
#pragma unroll
            for (int ks = 0; ks < 4; ++ks) {    // two chains of 4 (halve dep latency)
                short8 a0 = *(const short8*)(arow + ks * 32);
                short8 a1 = *(const short8*)(arow + (ks + 4) * 32);
                short8 b0f = *(const short8*)(w3l + (ks * 64 + lane) * 8);
                short8 b1f = *(const short8*)(w3l + ((ks + 4) * 64 + lane) * 8);
                accA = __builtin_amdgcn_mfma_f32_16x16x32_bf16(b0f, a0, accA, 0, 0, 0);
                accB = __builtin_amdgcn_mfma_f32_16x16x32_bf16(b1f, a1, accB, 0, 0, 0);
            }
            // D^T: col = path p, row quad*4+r = output n. Lane(quad0,p): n=0..3;
            // lane(quad1,p): n=4 in reg 0. One shuffle brings s22 to quad0.
            const float4v s4 = accA + accB;
            const float s22r = __shfl(s4[0], (lane + 16) & 63);
            if (lane < 16) {
                const int p = lane;            // col == lane, quad == 0 here
                const float mu0 = s4[0];
                const float mu1 = s4[1];
                const float s11 = softplus_fast(s4[2]);
                const float s21 = s4[3];
                const float s22 = softplus_fast(s22r);
                const float ps0 = (t == 0) ? pbuf[p * 202 + 0] : st[p][0];
                const float ps1 = (t == 0) ? pbuf[p * 202 + 101] : st[p][1];
                const float n0 = softplus_fast(ps0 + DTf * mu0 + SQ * (s11 * e0));
                const float n1 = softplus_fast(ps1 + DTf * mu1 + SQ * (s21 * e0 + s22 * e1));
                st[p][0] = n0;
                st[p][1] = n1;
                pbuf[p * 202 + (t + 1)] = n0;
                pbuf[p * 202 + 101 + (t + 1)] = n1;
                mbuf[p * 200 + t * 2 + 0] = mu0;
                mbuf[p * 200 + t * 2 + 1] = mu1;
                sbuf[p * 400 + t * 4 + 0] = s11;
                sbuf[p * 400 + t * 4 + 1] = 0.0f;
                sbuf[p * 400 + t * 4 + 2] = s21;
                sbuf[p * 400 + t * 4 + 3] = s22;
            }
        }
        __syncthreads();                       // E: st ready for next layer0
    }

    // ---- coalesced output write phase ----
    float* __restrict__ pdst = out + (size_t)pbase * 202;
    float* __restrict__ mdst = out + (size_t)PP * 202 + (size_t)pbase * 200;
    float* __restrict__ sdst = out + (size_t)PP * 202 + (size_t)PP * 200 + (size_t)pbase * 400;
    for (int i = tid; i < PB * 202 / 4; i += NT) ((float4*)pdst)[i] = ((const float4*)pbuf)[i];
    for (int i = tid; i < PB * 200 / 4; i += NT) ((float4*)mdst)[i] = ((const float4*)mbuf)[i];
    for (int i = tid; i < PB * 400 / 4; i += NT) ((float4*)sdst)[i] = ((const float4*)sbuf)[i];
}

extern "C" void kernel_launch(void* const* d_in, const int* in_sizes, int n_in,
                              void* d_out, int out_size, void* d_ws, size_t ws_size,
                              hipStream_t stream) {
    (void)in_sizes; (void)n_in; (void)out_size; (void)ws_size;
    float* cfeat = (float*)d_ws;             // 100*256 fp32 = 100 KB
    prep_cfeat<<<LT - 1, 256, 0, stream>>>(
        (const float*)d_in[0],   // W0
        (const float*)d_in[1],   // b0
        (const float*)d_in[9],   // feature_init (t0)
        (const float*)d_in[10],  // tn_store
        (const float*)d_in[11],  // x1_store
        (const float*)d_in[12],  // x2_store
        cfeat);
    lv_kernel<<<PP / PB, NT, 0, stream>>>(
        (const float*)d_in[0],   // W0
        (const float*)d_in[1],   // b0
        (const float*)d_in[2],   // W1
        (const float*)d_in[3],   // b1
        (const float*)d_in[4],   // W2
        (const float*)d_in[5],   // b2
        (const float*)d_in[6],   // W3
        (const float*)d_in[7],   // b3
        (const float*)d_in[8],   // obs_init
        (const float*)d_in[9],   // feature_init
        (const float*)d_in[13],  // path_seed
        cfeat,
        (float*)d_out);
}

// Round 9
// 267.073 us; speedup vs baseline: 1.0746x; 1.0373x over previous
//
#include <hip/hip_runtime.h>
#include <math.h>

// LotkaVolterra neural-SDE rollout. P=4096, H=256, 100 sequential steps.
// R24 = R23 (215us steady) + BARRIER-DRAIN FIX. gfx950 __syncthreads drains
// vmcnt(0) (guide m97: s_waitcnt vmcnt(0)... before s_barrier). The step loop
// had two per-step GLOBAL loads whose latency was eaten by the next barrier:
//  (a) path_seed: 16 lanes read a never-reused 128B row every step -> cold
//      HBM/L3 ~400-900 cyc drained at barB EVERY step. Fix: bulk-stage this
//      block's 12.8KB seed slice into LDS once at kernel start (coalesced);
//      tail reads 8B from LDS. LDS 87->99.8KB, still 1 block/CU.
//  (b) cfeat prefetch issued ~50cyc before barB -> barB ate its L2 latency.
//      Fix: issue it AFTER barB (top of L1 phase) -> drains at barC ~800cyc
//      later, fully hidden.
// This explains the ~2400-cyc gap between the throughput model (~2700) and
// the measured step (~5160). Everything else byte-identical to R23.
// Canary: VGPR 128, FETCH ~19.2MB, WRITE ~43.5MB must hold.

#define PP 4096
#define HH 256
#define LT 100
#define PB 16
#define SH 264          // bf16 LDS row stride: 528 B = 33*16B (MUST stay 16B-multiple)
#define NT 512

typedef __attribute__((ext_vector_type(8))) short short8;
typedef __attribute__((ext_vector_type(4))) short short4v;
typedef __attribute__((ext_vector_type(4))) float float4v;

__device__ __forceinline__ float softplus_fast(float x) {
    const float e = __expf(-fabsf(x));
    return fmaxf(x, 0.0f) + __logf(1.0f + e);
}
__device__ __forceinline__ unsigned short f2bf(float f) {   // RNE fp32->bf16
    unsigned int u = __float_as_uint(f);
    u += 0x7fffu + ((u >> 16) & 1u);
    return (unsigned short)(u >> 16);
}
// one-instruction packed RNE conversion: D = {lo16: bf16(a), hi16: bf16(b)}
__device__ __forceinline__ unsigned int cvtpk(float a, float b) {
    unsigned int r;
    asm("v_cvt_pk_bf16_f32 %0, %1, %2" : "=v"(r) : "v"(a), "v"(b));
    return r;
}
__device__ __forceinline__ float4 ldg4(const float* p) { return *(const float4*)p; }

// ---- parallel prologue: block b handles t = b+1 (R14-verified correct) ----
__global__ void prep_cfeat(const float* __restrict__ W0, const float* __restrict__ b0,
                           const float* __restrict__ feature_init,
                           const float* __restrict__ tn_store,
                           const float* __restrict__ x1_store,
                           const float* __restrict__ x2_store,
                           float* __restrict__ cfeat) {
    const int t = blockIdx.x + 1;             // 1..99
    const int col = threadIdx.x;
    // exact sequential fp32 tval chain (matches ref's scan accumulation)
    float tval = feature_init[0];
    for (int i = 0; i < t; ++i) tval += 0.1f;
    const float tn = tn_store[t - 1], x1 = x1_store[t - 1], x2 = x2_store[t - 1];
    const float w2c = W0[2 * 256 + col], w3c = W0[3 * 256 + col];
    const float w46 = W0[4 * 256 + col] + W0[6 * 256 + col];
    const float w57 = W0[5 * 256 + col] + W0[7 * 256 + col];
    cfeat[t * 256 + col] = b0[col] + tval * w2c + tn * w3c + x1 * w46 + x2 * w57;
}

// 256->256 bf16 MFMA layer, TWO ADJACENT col-groups/wave (paired-col mapping):
// acc0 = even cols wv*32+2c, acc1 = odd cols wv*32+2c+1 -> one cvt_pk + one
// b32 store per r (epilogue = 4 fmax-pairs + 4 cvt_pk + 4 ds_write_b32).
__device__ __forceinline__ void mfma256_reg2(const short8 (&wf)[2][8], float bv0, float bv1,
                                             const unsigned short* __restrict__ hin,
                                             unsigned short* __restrict__ hout,
                                             int wv, int lane) {
    const int quad = lane >> 4, col = lane & 15;
    float4v acc0 = {bv0, bv0, bv0, bv0};
    float4v acc1 = {bv1, bv1, bv1, bv1};
    const unsigned short* arow = hin + col * SH + quad * 8;
#pragma unroll
    for (int ks = 0; ks < 8; ++ks) {
        short8 a = *(const short8*)(arow + ks * 32);
        acc0 = __builtin_amdgcn_mfma_f32_16x16x32_bf16(a, wf[0][ks], acc0, 0, 0, 0);
        acc1 = __builtin_amdgcn_mfma_f32_16x16x32_bf16(a, wf[1][ks], acc1, 0, 0, 0);
    }
    // C/D layout: col = lane&15, row p = quad*4 + reg (m89-verified).
#pragma unroll
    for (int r = 0; r < 4; ++r) {
        const unsigned int pk = cvtpk(fmaxf(acc0[r], 0.0f), fmaxf(acc1[r], 0.0f));
        *(unsigned int*)&hout[(quad * 4 + r) * SH + wv * 32 + 2 * col] = pk;
    }
}

__global__ __launch_bounds__(NT, 2)
void lv_kernel(const float* __restrict__ W0, const float* __restrict__ b0,
               const float* __restrict__ W1, const float* __restrict__ b1,
               const float* __restrict__ W2, const float* __restrict__ b2,
               const float* __restrict__ W3, const float* __restrict__ b3,
               const float* __restrict__ obs_init, const float* __restrict__ feature_init,
               const float* __restrict__ path_seed,
               const float* __restrict__ cfeat,
               float* __restrict__ out) {
    __shared__ unsigned short hA[PB * SH];
    __shared__ unsigned short hB[PB * SH];
    __shared__ unsigned short hC[PB * SH];
    __shared__ __align__(16) unsigned short w3l[4096];   // W3 fragments (zero-padded)
    __shared__ __align__(16) float w0l[512];             // W0 rows 0,1
    __shared__ __align__(16) float sseed[LT * 32];       // ALL seeds for this block (12.8KB)
    __shared__ float st[PB][2];                          // path state
    __shared__ __align__(16) float pbuf[PB * 202];
    __shared__ __align__(16) float mbuf[PB * 200];
    __shared__ __align__(16) float sbuf[PB * 400];

    const int tid = threadIdx.x;
    const int lane = tid & 63;
    const int wv = tid >> 6;            // wave 0..7; owns col pairs wv*32+2c,+1
    const int quad = lane >> 4;
    const int col = lane & 15;
    const int hl = lane & 31;           // half-lane id (layer-0 col index base)
    const int lp = 2 * wv + (lane >> 5);// layer-0 path handled by this lane
    const int pbase = blockIdx.x * PB;

    const float DTf = 0.1f;
    const float SQ = 0.31622776601683794f;  // sqrt(0.1)

    // ---- per-wave W1/W2 B-fragments (2 ADJACENT col-groups) from global ----
    short8 wf1[2][8], wf2[2][8];
    {
#pragma unroll
        for (int g = 0; g < 2; ++g) {
            const int colc = wv * 32 + 2 * col + g;
#pragma unroll
            for (int ks = 0; ks < 8; ++ks) {
#pragma unroll
                for (int j = 0; j < 8; ++j) {
                    const int k = ks * 32 + quad * 8 + j;
                    wf1[g][ks][j] = (short)f2bf(W1[k * 256 + colc]);
                    wf2[g][ks][j] = (short)f2bf(W2[k * 256 + colc]);
                }
            }
        }
    }
    // ---- stage W3 fragments into LDS (zero-padded to 16 cols) ----
    for (int e = tid; e < 4096; e += NT) {
        const int j = e & 7, ln = (e >> 3) & 63, ks = e >> 9;
        const int k = ks * 32 + (ln >> 4) * 8 + j;
        const int n = ln & 15;
        w3l[e] = (n < 5) ? f2bf(W3[k * 5 + n]) : (unsigned short)0;
    }
    w0l[tid] = W0[tid];                      // rows 0,1 (NT == 512 exactly)
    // ---- bulk-stage ALL path_seed rows for this block (coalesced, one-time) ----
    for (int e = tid; e < LT * 32; e += NT) {
        sseed[e] = path_seed[(size_t)(e >> 5) * (PP * 2) + (size_t)pbase * 2 + (e & 31)];
    }

    // step-invariant hoists (paired-col bias indices)
    const float bv1a = b1[wv * 32 + 2 * col];
    const float bv1b = b1[wv * 32 + 2 * col + 1];
    const float bv2a = b2[wv * 32 + 2 * col];
    const float bv2b = b2[wv * 32 + 2 * col + 1];
    float4v b3v;                          // tail bias, D^T row n = quad*4+r
#pragma unroll
    for (int r = 0; r < 4; ++r) {
        const int n = quad * 4 + r;
        b3v[r] = (n < 5) ? b3[n] : 0.0f;
    }

    if (tid < PB) {
        const int p = tid, gp = pbase + p;
        pbuf[p * 202 + 0] = obs_init[gp * 2 + 0];
        pbuf[p * 202 + 101] = obs_init[gp * 2 + 1];
    }

    // ---- t=0 layer 0: lane handles path lp, 8 cols starting at hl*8 ----
    {
        const int gp = pbase + lp;
        float xk[8];
        xk[0] = obs_init[gp * 2 + 0];
        xk[1] = obs_init[gp * 2 + 1];
#pragma unroll
        for (int f = 0; f < 6; ++f) xk[2 + f] = feature_init[gp * 6 + f];
        const int c0 = hl * 8;
        float a[8];
        {
            const float4 ba = ldg4(b0 + c0);
            const float4 bb = ldg4(b0 + c0 + 4);
            a[0] = ba.x; a[1] = ba.y; a[2] = ba.z; a[3] = ba.w;
            a[4] = bb.x; a[5] = bb.y; a[6] = bb.z; a[7] = bb.w;
        }
#pragma unroll
        for (int k = 0; k < 8; ++k) {
            const float4 wa = ldg4(W0 + k * HH + c0);
            const float4 wb = ldg4(W0 + k * HH + c0 + 4);
            a[0] = fmaf(xk[k], wa.x, a[0]); a[1] = fmaf(xk[k], wa.y, a[1]);
            a[2] = fmaf(xk[k], wa.z, a[2]); a[3] = fmaf(xk[k], wa.w, a[3]);
            a[4] = fmaf(xk[k], wb.x, a[4]); a[5] = fmaf(xk[k], wb.y, a[5]);
            a[6] = fmaf(xk[k], wb.z, a[6]); a[7] = fmaf(xk[k], wb.w, a[7]);
        }
        uint4 ov;
        ov.x = cvtpk(fmaxf(a[0], 0.0f), fmaxf(a[1], 0.0f));
        ov.y = cvtpk(fmaxf(a[2], 0.0f), fmaxf(a[3], 0.0f));
        ov.z = cvtpk(fmaxf(a[4], 0.0f), fmaxf(a[5], 0.0f));
        ov.w = cvtpk(fmaxf(a[6], 0.0f), fmaxf(a[7], 0.0f));
        *(uint4*)&hA[lp * SH + c0] = ov;
    }
    // preload cfeat for t=1 (8 cols per lane; one-time drain at first barB is fine)
    float4 cf0 = ldg4(cfeat + 256 + hl * 8);
    float4 cf1 = ldg4(cfeat + 256 + hl * 8 + 4);

    for (int t = 0; t < LT; ++t) {
        // ---- layer 0 (t>=1): lane = path lp, 8 cols; st from LDS broadcast ----
        if (t > 0) {
            const float s0 = st[lp][0];
            const float s1 = st[lp][1];
            const int c0 = hl * 8;
            const float4 wa0 = *(const float4*)&w0l[c0];
            const float4 wa1 = *(const float4*)&w0l[c0 + 4];
            const float4 wb0 = *(const float4*)&w0l[256 + c0];
            const float4 wb1 = *(const float4*)&w0l[256 + c0 + 4];
            uint4 ov;
            ov.x = cvtpk(fmaxf(fmaf(s0, wa0.x, fmaf(s1, wb0.x, cf0.x)), 0.0f),
                         fmaxf(fmaf(s0, wa0.y, fmaf(s1, wb0.y, cf0.y)), 0.0f));
            ov.y = cvtpk(fmaxf(fmaf(s0, wa0.z, fmaf(s1, wb0.z, cf0.z)), 0.0f),
                         fmaxf(fmaf(s0, wa0.w, fmaf(s1, wb0.w, cf0.w)), 0.0f));
            ov.z = cvtpk(fmaxf(fmaf(s0, wa1.x, fmaf(s1, wb1.x, cf1.x)), 0.0f),
                         fmaxf(fmaf(s0, wa1.y, fmaf(s1, wb1.y, cf1.y)), 0.0f));
            ov.w = cvtpk(fmaxf(fmaf(s0, wa1.z, fmaf(s1, wb1.z, cf1.z)), 0.0f),
                         fmaxf(fmaf(s0, wa1.w, fmaf(s1, wb1.w, cf1.w)), 0.0f));
            *(uint4*)&hA[lp * SH + c0] = ov;
        }
        __syncthreads();                       // B: h0 (hA) ready (drains LDS only now)

        // prefetch next step's cfeat HERE: drains at barC ~800cyc later -> hidden
        {
            const int ti = (t + 1 < LT) ? (t + 1) : (LT - 1);
            cf0 = ldg4(cfeat + ti * 256 + hl * 8);
            cf1 = ldg4(cfeat + ti * 256 + hl * 8 + 4);
        }

        mfma256_reg2(wf1, bv1a, bv1b, hA, hB, wv, lane);   // h1 = relu(h0 @ W1 + b1)
        __syncthreads();                       // C: h1 (hB) ready
        mfma256_reg2(wf2, bv2a, bv2b, hB, hC, wv, lane);   // h2 = relu(h1 @ W2 + b2)
        __syncthreads();                       // D: h2 (hC) ready

        // ---- layer 3 + sampling: WAVE 0 ONLY. Operand-SWAPPED MFMA with W3
        //      frags from LDS (R18-verified); __shfl epilogue (R19-verified). ----
        if (wv == 0) {
            float4v accA = b3v;
            float4v accB = {0.0f, 0.0f, 0.0f, 0.0f};
            const unsigned short* arow = hC + col * SH + quad * 8;
#pragma unroll
            for (int ks = 0; ks < 4; ++ks) {    // two chains of 4 (halve dep latency)
                short8 a0 = *(const short8*)(arow + ks * 32);
                short8 a1 = *(const short8*)(arow + (ks + 4) * 32);
                short8 b0f = *(const short8*)(w3l + (ks * 64 + lane) * 8);
                short8 b1f = *(const short8*)(w3l + ((ks + 4) * 64 + lane) * 8);
                accA = __builtin_amdgcn_mfma_f32_16x16x32_bf16(b0f, a0, accA, 0, 0, 0);
                accB = __builtin_amdgcn_mfma_f32_16x16x32_bf16(b1f, a1, accB, 0, 0, 0);
            }
            // D^T: col = path p, row quad*4+r = output n. Lane(quad0,p): n=0..3;
            // lane(quad1,p): n=4 in reg 0. One shuffle brings s22 to quad0.
            const float4v s4 = accA + accB;
            const float s22r = __shfl(s4[0], (lane + 16) & 63);
            if (lane < 16) {
                const int p = lane;            // col == lane, quad == 0 here
                const float e0 = sseed[t * 32 + 2 * p];       // LDS, no vmcnt drain
                const float e1 = sseed[t * 32 + 2 * p + 1];
                const float mu0 = s4[0];
                const float mu1 = s4[1];
                const float s11 = softplus_fast(s4[2]);
                const float s21 = s4[3];
                const float s22 = softplus_fast(s22r);
                const float ps0 = (t == 0) ? pbuf[p * 202 + 0] : st[p][0];
                const float ps1 = (t == 0) ? pbuf[p * 202 + 101] : st[p][1];
                const float n0 = softplus_fast(ps0 + DTf * mu0 + SQ * (s11 * e0));
                const float n1 = softplus_fast(ps1 + DTf * mu1 + SQ * (s21 * e0 + s22 * e1));
                st[p][0] = n0;
                st[p][1] = n1;
                pbuf[p * 202 + (t + 1)] = n0;
                pbuf[p * 202 + 101 + (t + 1)] = n1;
                mbuf[p * 200 + t * 2 + 0] = mu0;
                mbuf[p * 200 + t * 2 + 1] = mu1;
                sbuf[p * 400 + t * 4 + 0] = s11;
                sbuf[p * 400 + t * 4 + 1] = 0.0f;
                sbuf[p * 400 + t * 4 + 2] = s21;
                sbuf[p * 400 + t * 4 + 3] = s22;
            }
        }
        __syncthreads();                       // E: st ready for next layer0
    }

    // ---- coalesced output write phase ----
    float* __restrict__ pdst = out + (size_t)pbase * 202;
    float* __restrict__ mdst = out + (size_t)PP * 202 + (size_t)pbase * 200;
    float* __restrict__ sdst = out + (size_t)PP * 202 + (size_t)PP * 200 + (size_t)pbase * 400;
    for (int i = tid; i < PB * 202 / 4; i += NT) ((float4*)pdst)[i] = ((const float4*)pbuf)[i];
    for (int i = tid; i < PB * 200 / 4; i += NT) ((float4*)mdst)[i] = ((const float4*)mbuf)[i];
    for (int i = tid; i < PB * 400 / 4; i += NT) ((float4*)sdst)[i] = ((const float4*)sbuf)[i];
}

extern "C" void kernel_launch(void* const* d_in, const int* in_sizes, int n_in,
                              void* d_out, int out_size, void* d_ws, size_t ws_size,
                              hipStream_t stream) {
    (void)in_sizes; (void)n_in; (void)out_size; (void)ws_size;
    float* cfeat = (float*)d_ws;             // 100*256 fp32 = 100 KB
    prep_cfeat<<<LT - 1, 256, 0, stream>>>(
        (const float*)d_in[0],   // W0
        (const float*)d_in[1],   // b0
        (const float*)d_in[9],   // feature_init (t0)
        (const float*)d_in[10],  // tn_store
        (const float*)d_in[11],  // x1_store
        (const float*)d_in[12],  // x2_store
        cfeat);
    lv_kernel<<<PP / PB, NT, 0, stream>>>(
        (const float*)d_in[0],   // W0
        (const float*)d_in[1],   // b0
        (const float*)d_in[2],   // W1
        (const float*)d_in[3],   // b1
        (const float*)d_in[4],   // W2
        (const float*)d_in[5],   // b2
        (const float*)d_in[6],   // W3
        (const float*)d_in[7],   // b3
        (const float*)d_in[8],   // obs_init
        (const float*)d_in[9],   // feature_init
        (const float*)d_in[13],  // path_seed
        cfeat,
        (float*)d_out);
}